// Round 1
// 987.128 us; speedup vs baseline: 1.3982x; 1.3982x over previous
//
#include <hip/hip_runtime.h>

#define NN 50000
#define TT 10
#define EE 1000000

__device__ __forceinline__ float sigmoidf_(float v) { return 1.0f / (1.0f + __expf(-v)); }
__device__ __forceinline__ float reluf_(float v) { return v > 0.0f ? v : 0.0f; }

// MLP1: feat[9] -> relu(9x32) -> relu(32x32) -> sigmoid(32x1)
// Weights read straight from global const __restrict__ pointers with
// compile-time indices -> uniform addresses -> compiler emits s_load
// (SGPR operands for v_fmac), no LDS, no per-MAC vector memory op.
// Loops are weight-streaming order (contiguous inner index) so the
// scalar loads vectorize to s_load_dwordx8/x16.
__device__ __forceinline__ float mlp1_eval_g(const float* feat,
                                             const float* __restrict__ w1,
                                             const float* __restrict__ b1,
                                             const float* __restrict__ w2,
                                             const float* __restrict__ b2,
                                             const float* __restrict__ w3,
                                             const float* __restrict__ b3) {
    float h1[32];
#pragma unroll
    for (int j = 0; j < 32; ++j) h1[j] = b1[j];
#pragma unroll
    for (int i = 0; i < 9; ++i) {
        float f = feat[i];
#pragma unroll
        for (int j = 0; j < 32; ++j) h1[j] += f * w1[i * 32 + j];
    }
#pragma unroll
    for (int j = 0; j < 32; ++j) h1[j] = reluf_(h1[j]);

    float h2[32];
#pragma unroll
    for (int j = 0; j < 32; ++j) h2[j] = b2[j];
#pragma unroll
    for (int i = 0; i < 32; ++i) {
        float f = h1[i];
#pragma unroll
        for (int j = 0; j < 32; ++j) h2[j] += f * w2[i * 32 + j];
    }
    float acc = b3[0];
#pragma unroll
    for (int j = 0; j < 32; ++j) acc += reluf_(h2[j]) * w3[j];
    return sigmoidf_(acc);
}

// Pre-pass: transpose ea -> eaT[t][e], x -> x0T[t][n], x1T[t][n] (if tflag),
// and do the old init (hidden=0, agg=0, msg_base for frame 0).
__global__ void pre_kernel(const float* __restrict__ x,
                           const float* __restrict__ ea,
                           const float* __restrict__ w1, const float* __restrict__ b1,
                           const float* __restrict__ w2, const float* __restrict__ b2,
                           const float* __restrict__ w3, const float* __restrict__ b3,
                           float* __restrict__ hidden, float* __restrict__ msg_base,
                           float* __restrict__ agg,
                           float* __restrict__ x0T, float* __restrict__ x1T,
                           float* __restrict__ eaT, int tflag) {
    int g = blockIdx.x * blockDim.x + threadIdx.x;
    if (tflag) {
        if (g < EE) {
            const float2* row = reinterpret_cast<const float2*>(ea + (size_t)g * TT);
            float v[TT];
#pragma unroll
            for (int c = 0; c < 5; ++c) { float2 p = row[c]; v[2 * c] = p.x; v[2 * c + 1] = p.y; }
#pragma unroll
            for (int tt = 0; tt < TT; ++tt) eaT[(size_t)tt * EE + g] = v[tt];
        }
        if (g < NN) {
            const float2* xr = reinterpret_cast<const float2*>(x + (size_t)g * TT * 2);
            float x0v[TT], x1v[TT];
#pragma unroll
            for (int tt = 0; tt < TT; ++tt) { float2 p = xr[tt]; x0v[tt] = p.x; x1v[tt] = p.y; }
#pragma unroll
            for (int tt = 0; tt < TT; ++tt) { x0T[tt * NN + g] = x0v[tt]; x1T[tt * NN + g] = x1v[tt]; }
            float feat[9];
            feat[0] = x0v[0];
#pragma unroll
            for (int k = 0; k < 8; ++k) feat[1 + k] = 0.0f;
            msg_base[g] = mlp1_eval_g(feat, w1, b1, w2, b2, w3, b3);
            agg[g] = 0.0f;
#pragma unroll
            for (int k = 0; k < 8; ++k) hidden[g * 8 + k] = 0.0f;
        }
    } else {
        if (g < NN) {
            float feat[9];
            feat[0] = x[(size_t)g * TT * 2];
#pragma unroll
            for (int k = 0; k < 8; ++k) feat[1 + k] = 0.0f;
            msg_base[g] = mlp1_eval_g(feat, w1, b1, w2, b2, w3, b3);
            agg[g] = 0.0f;
#pragma unroll
            for (int k = 0; k < 8; ++k) hidden[g * 8 + k] = 0.0f;
        }
    }
}

// Edge scatter: agg[dst] += msg_base[src] * ea[e,t]; 2 edges/thread
// (doubles wave count vs 4/thread -> ~7.6 waves/SIMD for latency hiding).
__global__ void edge_kernel(const int* __restrict__ ei, const float* __restrict__ ea,
                            const float* __restrict__ eaT,
                            const float* __restrict__ msg_base, float* __restrict__ agg,
                            int t, int tflag) {
    int g = blockIdx.x * blockDim.x + threadIdx.x;
    int e0 = g * 2;
    if (e0 >= EE) return;
    const int2 s = *reinterpret_cast<const int2*>(ei + (size_t)t * EE + e0);
    const int2 d = *reinterpret_cast<const int2*>(ei + (size_t)(TT + t) * EE + e0);
    float ev0, ev1;
    if (tflag) {
        float2 ev = *reinterpret_cast<const float2*>(eaT + (size_t)t * EE + e0);
        ev0 = ev.x; ev1 = ev.y;
    } else {
        ev0 = ea[(size_t)e0 * TT + t];
        ev1 = ea[(size_t)(e0 + 1) * TT + t];
    }
    float m0 = msg_base[s.x] * ev0;
    float m1 = msg_base[s.y] * ev1;
    atomicAdd(&agg[d.x], m0);
    atomicAdd(&agg[d.y], m1);
}

// Node update for frame t. No LDS; weights via uniform (scalar) loads.
__global__ void node_kernel(const float* __restrict__ x,
                            const float* __restrict__ x0T, const float* __restrict__ x1T,
                            const float* __restrict__ m1w1, const float* __restrict__ m1b1,
                            const float* __restrict__ m1w2, const float* __restrict__ m1b2,
                            const float* __restrict__ m1w3, const float* __restrict__ m1b3,
                            const float* __restrict__ m2w1, const float* __restrict__ m2b1,
                            const float* __restrict__ m2w2, const float* __restrict__ m2b2,
                            const float* __restrict__ ow1, const float* __restrict__ ob1,
                            const float* __restrict__ ow2, const float* __restrict__ ob2,
                            float* __restrict__ hidden, float* __restrict__ msg_base,
                            float* __restrict__ agg, float* __restrict__ out,
                            int t, int tflag) {
    int n = blockIdx.x * blockDim.x + threadIdx.x;
    if (n >= NN) return;

    float hid[8];
#pragma unroll
    for (int k = 0; k < 8; ++k) hid[k] = hidden[n * 8 + k];
    float x1 = tflag ? x1T[t * NN + n] : x[(size_t)n * TT * 2 + t * 2 + 1];
    float a = agg[n];

    float uin[10];
    uin[0] = x1;
#pragma unroll
    for (int k = 0; k < 8; ++k) uin[1 + k] = hid[k];
    uin[9] = a;

    float u1[32];
#pragma unroll
    for (int j = 0; j < 32; ++j) u1[j] = m2b1[j];
#pragma unroll
    for (int i = 0; i < 10; ++i) {
        float f = uin[i];
#pragma unroll
        for (int j = 0; j < 32; ++j) u1[j] += f * m2w1[i * 32 + j];
    }
#pragma unroll
    for (int j = 0; j < 32; ++j) u1[j] = reluf_(u1[j]);

    float hn[8];
#pragma unroll
    for (int k = 0; k < 8; ++k) hn[k] = m2b2[k];
#pragma unroll
    for (int j = 0; j < 32; ++j) {
        float f = u1[j];
#pragma unroll
        for (int k = 0; k < 8; ++k) hn[k] += f * m2w2[j * 8 + k];
    }
#pragma unroll
    for (int k = 0; k < 8; ++k) hn[k] = tanhf(reluf_(hn[k]));
#pragma unroll
    for (int k = 0; k < 8; ++k) hidden[n * 8 + k] = hn[k];

    float o1[16];
#pragma unroll
    for (int l = 0; l < 16; ++l) o1[l] = ob1[l];
#pragma unroll
    for (int k = 0; k < 8; ++k) {
        float f = hn[k];
#pragma unroll
        for (int l = 0; l < 16; ++l) o1[l] += f * ow1[k * 16 + l];
    }
    float oo = ob2[0];
#pragma unroll
    for (int l = 0; l < 16; ++l) oo += reluf_(o1[l]) * ow2[l];
    out[t * NN + n] = sigmoidf_(oo);

    if (t < TT - 1) {
        float feat[9];
        feat[0] = tflag ? x0T[(t + 1) * NN + n] : x[(size_t)n * TT * 2 + (t + 1) * 2];
#pragma unroll
        for (int k = 0; k < 8; ++k) feat[1 + k] = hn[k];
        msg_base[n] = mlp1_eval_g(feat, m1w1, m1b1, m1w2, m1b2, m1w3, m1b3);
        agg[n] = 0.0f;
    }
}

extern "C" void kernel_launch(void* const* d_in, const int* in_sizes, int n_in,
                              void* d_out, int out_size, void* d_ws, size_t ws_size,
                              hipStream_t stream) {
    (void)in_sizes; (void)n_in; (void)out_size;
    const float* x    = (const float*)d_in[0];
    const int*   ei   = (const int*)d_in[1];
    const float* ea   = (const float*)d_in[2];
    const float* m1w1 = (const float*)d_in[3];
    const float* m1b1 = (const float*)d_in[4];
    const float* m1w2 = (const float*)d_in[5];
    const float* m1b2 = (const float*)d_in[6];
    const float* m1w3 = (const float*)d_in[7];
    const float* m1b3 = (const float*)d_in[8];
    const float* m2w1 = (const float*)d_in[9];
    const float* m2b1 = (const float*)d_in[10];
    const float* m2w2 = (const float*)d_in[11];
    const float* m2b2 = (const float*)d_in[12];
    const float* ow1  = (const float*)d_in[13];
    const float* ob1  = (const float*)d_in[14];
    const float* ow2  = (const float*)d_in[15];
    const float* ob2  = (const float*)d_in[16];
    float* out = (float*)d_out;

    float* hidden   = (float*)d_ws;             // NN*8
    float* msg_base = hidden + (size_t)NN * 8;  // NN
    float* agg      = msg_base + NN;            // NN
    float* x0T      = agg + NN;                 // NN*TT
    float* x1T      = x0T + (size_t)NN * TT;    // NN*TT
    float* eaT      = x1T + (size_t)NN * TT;    // EE*TT (40 MB)

    size_t need = ((size_t)NN * 10 + (size_t)NN * TT * 2 + (size_t)EE * TT) * sizeof(float);
    int tflag = (ws_size >= need) ? 1 : 0;

    dim3 blk(256);
    int nodeBlocks = (NN + 255) / 256;
    int preBlocks  = tflag ? (EE + 255) / 256 : nodeBlocks;
    int edgeBlocks = (EE / 2 + 255) / 256;

    pre_kernel<<<preBlocks, blk, 0, stream>>>(x, ea, m1w1, m1b1, m1w2, m1b2, m1w3, m1b3,
                                              hidden, msg_base, agg, x0T, x1T, eaT, tflag);
    for (int t = 0; t < TT; ++t) {
        edge_kernel<<<edgeBlocks, blk, 0, stream>>>(ei, ea, eaT, msg_base, agg, t, tflag);
        node_kernel<<<nodeBlocks, blk, 0, stream>>>(x, x0T, x1T,
                                                    m1w1, m1b1, m1w2, m1b2, m1w3, m1b3,
                                                    m2w1, m2b1, m2w2, m2b2,
                                                    ow1, ob1, ow2, ob2,
                                                    hidden, msg_base, agg, out, t, tflag);
    }
}

// Round 2
// 906.845 us; speedup vs baseline: 1.5220x; 1.0885x over previous
//
#include <hip/hip_runtime.h>

#define NN 50000
#define TT 10
#define EE 1000000

// Edge-binning geometry: EB blocks * EBT threads * KPT edges >= EE
#define EB 128
#define EBT 1024
#define KPT 8
#define PART 12500   // nodes per LDS partition (48.8 KB)
#define NPASS 4      // PART * NPASS == NN

__device__ __forceinline__ float sigmoidf_(float v) { return 1.0f / (1.0f + __expf(-v)); }
__device__ __forceinline__ float reluf_(float v) { return v > 0.0f ? v : 0.0f; }

// MLP1: feat[9] -> relu(9x32) -> relu(32x32) -> sigmoid(32x1)
// Weights read from global const __restrict__ with compile-time indices ->
// scalarized to s_load; weight-streaming loop order.
__device__ __forceinline__ float mlp1_eval_g(const float* feat,
                                             const float* __restrict__ w1,
                                             const float* __restrict__ b1,
                                             const float* __restrict__ w2,
                                             const float* __restrict__ b2,
                                             const float* __restrict__ w3,
                                             const float* __restrict__ b3) {
    float h1[32];
#pragma unroll
    for (int j = 0; j < 32; ++j) h1[j] = b1[j];
#pragma unroll
    for (int i = 0; i < 9; ++i) {
        float f = feat[i];
#pragma unroll
        for (int j = 0; j < 32; ++j) h1[j] += f * w1[i * 32 + j];
    }
#pragma unroll
    for (int j = 0; j < 32; ++j) h1[j] = reluf_(h1[j]);

    float h2[32];
#pragma unroll
    for (int j = 0; j < 32; ++j) h2[j] = b2[j];
#pragma unroll
    for (int i = 0; i < 32; ++i) {
        float f = h1[i];
#pragma unroll
        for (int j = 0; j < 32; ++j) h2[j] += f * w2[i * 32 + j];
    }
    float acc = b3[0];
#pragma unroll
    for (int j = 0; j < 32; ++j) acc += reluf_(h2[j]) * w3[j];
    return sigmoidf_(acc);
}

// Pre-pass: transpose x -> x0T/x1T (if binned), init hidden/msg_base (+agg for legacy).
__global__ void pre_kernel(const float* __restrict__ x,
                           const float* __restrict__ w1, const float* __restrict__ b1,
                           const float* __restrict__ w2, const float* __restrict__ b2,
                           const float* __restrict__ w3, const float* __restrict__ b3,
                           float* __restrict__ hidden, float* __restrict__ msg_base,
                           float* __restrict__ agg,
                           float* __restrict__ x0T, float* __restrict__ x1T,
                           int binned) {
    int g = blockIdx.x * blockDim.x + threadIdx.x;
    if (g >= NN) return;
    float x00;
    if (binned) {
        const float2* xr = reinterpret_cast<const float2*>(x + (size_t)g * TT * 2);
        float x0v[TT], x1v[TT];
#pragma unroll
        for (int tt = 0; tt < TT; ++tt) { float2 p = xr[tt]; x0v[tt] = p.x; x1v[tt] = p.y; }
#pragma unroll
        for (int tt = 0; tt < TT; ++tt) { x0T[tt * NN + g] = x0v[tt]; x1T[tt * NN + g] = x1v[tt]; }
        x00 = x0v[0];
    } else {
        x00 = x[(size_t)g * TT * 2];
        agg[g] = 0.0f;
    }
    float feat[9];
    feat[0] = x00;
#pragma unroll
    for (int k = 0; k < 8; ++k) feat[1 + k] = 0.0f;
    msg_base[g] = mlp1_eval_g(feat, w1, b1, w2, b2, w3, b3);
#pragma unroll
    for (int k = 0; k < 8; ++k) hidden[g * 8 + k] = 0.0f;
}

// Binned edge aggregation: no device atomics.
// Each block: load its 8192 edges once into regs (dst, msg), then 4 passes
// over 12.5K-node partitions accumulating in LDS, flush coalesced into a
// per-block copy aggB[b][n].
__global__ __launch_bounds__(EBT) void edge_bin_kernel(const int* __restrict__ ei,
                                                       const float* __restrict__ ea,
                                                       const float* __restrict__ msg_base,
                                                       float* __restrict__ aggB, int t) {
    __shared__ float lacc[PART];
    const int tid = threadIdx.x;
    const int b = blockIdx.x;

    int d[KPT];
    float m[KPT];
#pragma unroll
    for (int k = 0; k < KPT; ++k) {
        int e = b * (EBT * KPT) + k * EBT + tid;
        if (e < EE) {
            d[k] = ei[(size_t)(TT + t) * EE + e];
            int s = ei[(size_t)t * EE + e];
            m[k] = msg_base[s] * ea[(size_t)e * TT + t];
        } else {
            d[k] = -1;
            m[k] = 0.0f;
        }
    }

#pragma unroll
    for (int p = 0; p < NPASS; ++p) {
        const int lo = p * PART;
        for (int i = tid; i < PART; i += EBT) lacc[i] = 0.0f;
        __syncthreads();
#pragma unroll
        for (int k = 0; k < KPT; ++k) {
            int r = d[k] - lo;
            if ((unsigned)r < (unsigned)PART) atomicAdd(&lacc[r], m[k]);
        }
        __syncthreads();
        for (int i = tid; i < PART; i += EBT) aggB[(size_t)b * NN + lo + i] = lacc[i];
        __syncthreads();
    }
}

// Legacy fallback: device-atomic scatter (used only if workspace too small).
__global__ void edge_kernel(const int* __restrict__ ei, const float* __restrict__ ea,
                            const float* __restrict__ msg_base, float* __restrict__ agg,
                            int t) {
    int g = blockIdx.x * blockDim.x + threadIdx.x;
    int e0 = g * 2;
    if (e0 >= EE) return;
    const int2 s = *reinterpret_cast<const int2*>(ei + (size_t)t * EE + e0);
    const int2 d = *reinterpret_cast<const int2*>(ei + (size_t)(TT + t) * EE + e0);
    float ev0 = ea[(size_t)e0 * TT + t];
    float ev1 = ea[(size_t)(e0 + 1) * TT + t];
    atomicAdd(&agg[d.x], msg_base[s.x] * ev0);
    atomicAdd(&agg[d.y], msg_base[s.y] * ev1);
}

// Node update for frame t. Weights via uniform scalar loads; agg via
// reduction over the EB per-block copies (binned) or agg[] (legacy).
__global__ void node_kernel(const float* __restrict__ x,
                            const float* __restrict__ x0T, const float* __restrict__ x1T,
                            const float* __restrict__ m1w1, const float* __restrict__ m1b1,
                            const float* __restrict__ m1w2, const float* __restrict__ m1b2,
                            const float* __restrict__ m1w3, const float* __restrict__ m1b3,
                            const float* __restrict__ m2w1, const float* __restrict__ m2b1,
                            const float* __restrict__ m2w2, const float* __restrict__ m2b2,
                            const float* __restrict__ ow1, const float* __restrict__ ob1,
                            const float* __restrict__ ow2, const float* __restrict__ ob2,
                            float* __restrict__ hidden, float* __restrict__ msg_base,
                            float* __restrict__ agg, const float* __restrict__ aggB,
                            float* __restrict__ out, int t, int binned) {
    int n = blockIdx.x * blockDim.x + threadIdx.x;
    if (n >= NN) return;

    float hid[8];
#pragma unroll
    for (int k = 0; k < 8; ++k) hid[k] = hidden[n * 8 + k];

    float a;
    if (binned) {
        const float* ab = aggB + n;
        float a0 = 0.f, a1 = 0.f, a2 = 0.f, a3 = 0.f;
#pragma unroll
        for (int b = 0; b < EB; b += 4) {
            a0 += ab[(size_t)(b + 0) * NN];
            a1 += ab[(size_t)(b + 1) * NN];
            a2 += ab[(size_t)(b + 2) * NN];
            a3 += ab[(size_t)(b + 3) * NN];
        }
        a = (a0 + a1) + (a2 + a3);
    } else {
        a = agg[n];
    }

    float x1 = binned ? x1T[t * NN + n] : x[(size_t)n * TT * 2 + t * 2 + 1];

    float uin[10];
    uin[0] = x1;
#pragma unroll
    for (int k = 0; k < 8; ++k) uin[1 + k] = hid[k];
    uin[9] = a;

    float u1[32];
#pragma unroll
    for (int j = 0; j < 32; ++j) u1[j] = m2b1[j];
#pragma unroll
    for (int i = 0; i < 10; ++i) {
        float f = uin[i];
#pragma unroll
        for (int j = 0; j < 32; ++j) u1[j] += f * m2w1[i * 32 + j];
    }
#pragma unroll
    for (int j = 0; j < 32; ++j) u1[j] = reluf_(u1[j]);

    float hn[8];
#pragma unroll
    for (int k = 0; k < 8; ++k) hn[k] = m2b2[k];
#pragma unroll
    for (int j = 0; j < 32; ++j) {
        float f = u1[j];
#pragma unroll
        for (int k = 0; k < 8; ++k) hn[k] += f * m2w2[j * 8 + k];
    }
#pragma unroll
    for (int k = 0; k < 8; ++k) hn[k] = tanhf(reluf_(hn[k]));
#pragma unroll
    for (int k = 0; k < 8; ++k) hidden[n * 8 + k] = hn[k];

    float o1[16];
#pragma unroll
    for (int l = 0; l < 16; ++l) o1[l] = ob1[l];
#pragma unroll
    for (int k = 0; k < 8; ++k) {
        float f = hn[k];
#pragma unroll
        for (int l = 0; l < 16; ++l) o1[l] += f * ow1[k * 16 + l];
    }
    float oo = ob2[0];
#pragma unroll
    for (int l = 0; l < 16; ++l) oo += reluf_(o1[l]) * ow2[l];
    out[t * NN + n] = sigmoidf_(oo);

    if (t < TT - 1) {
        float feat[9];
        feat[0] = binned ? x0T[(t + 1) * NN + n] : x[(size_t)n * TT * 2 + (t + 1) * 2];
#pragma unroll
        for (int k = 0; k < 8; ++k) feat[1 + k] = hn[k];
        msg_base[n] = mlp1_eval_g(feat, m1w1, m1b1, m1w2, m1b2, m1w3, m1b3);
        if (!binned) agg[n] = 0.0f;
    }
}

extern "C" void kernel_launch(void* const* d_in, const int* in_sizes, int n_in,
                              void* d_out, int out_size, void* d_ws, size_t ws_size,
                              hipStream_t stream) {
    (void)in_sizes; (void)n_in; (void)out_size;
    const float* x    = (const float*)d_in[0];
    const int*   ei   = (const int*)d_in[1];
    const float* ea   = (const float*)d_in[2];
    const float* m1w1 = (const float*)d_in[3];
    const float* m1b1 = (const float*)d_in[4];
    const float* m1w2 = (const float*)d_in[5];
    const float* m1b2 = (const float*)d_in[6];
    const float* m1w3 = (const float*)d_in[7];
    const float* m1b3 = (const float*)d_in[8];
    const float* m2w1 = (const float*)d_in[9];
    const float* m2b1 = (const float*)d_in[10];
    const float* m2w2 = (const float*)d_in[11];
    const float* m2b2 = (const float*)d_in[12];
    const float* ow1  = (const float*)d_in[13];
    const float* ob1  = (const float*)d_in[14];
    const float* ow2  = (const float*)d_in[15];
    const float* ob2  = (const float*)d_in[16];
    float* out = (float*)d_out;

    float* hidden   = (float*)d_ws;             // NN*8
    float* msg_base = hidden + (size_t)NN * 8;  // NN
    float* agg      = msg_base + NN;            // NN (legacy only)
    float* x0T      = agg + NN;                 // NN*TT
    float* x1T      = x0T + (size_t)NN * TT;    // NN*TT
    float* aggB     = x1T + (size_t)NN * TT;    // EB*NN (25.6 MB)

    size_t need = ((size_t)NN * 10 + (size_t)NN * TT * 2 + (size_t)EB * NN) * sizeof(float);
    int binned = (ws_size >= need) ? 1 : 0;

    dim3 blk(256);
    int nodeBlocks = (NN + 255) / 256;
    int edgeBlocksLegacy = (EE / 2 + 255) / 256;

    pre_kernel<<<nodeBlocks, blk, 0, stream>>>(x, m1w1, m1b1, m1w2, m1b2, m1w3, m1b3,
                                               hidden, msg_base, agg, x0T, x1T, binned);
    for (int t = 0; t < TT; ++t) {
        if (binned) {
            edge_bin_kernel<<<EB, dim3(EBT), 0, stream>>>(ei, ea, msg_base, aggB, t);
        } else {
            edge_kernel<<<edgeBlocksLegacy, blk, 0, stream>>>(ei, ea, msg_base, agg, t);
        }
        node_kernel<<<nodeBlocks, blk, 0, stream>>>(x, x0T, x1T,
                                                    m1w1, m1b1, m1w2, m1b2, m1w3, m1b3,
                                                    m2w1, m2b1, m2w2, m2b2,
                                                    ow1, ob1, ow2, ob2,
                                                    hidden, msg_base, agg, aggB, out, t, binned);
    }
}

// Round 3
// 822.862 us; speedup vs baseline: 1.6773x; 1.1021x over previous
//
#include <hip/hip_runtime.h>

#define NN 50000
#define TT 10
#define EE 1000000

#define EBT 1024     // threads per edge block
#define PART 12500   // nodes per LDS partition (48.8 KB, stays under 64 KB static limit)
#define NPASS 4      // PART * NPASS == NN

__device__ __forceinline__ float sigmoidf_(float v) { return 1.0f / (1.0f + __expf(-v)); }
__device__ __forceinline__ float reluf_(float v) { return v > 0.0f ? v : 0.0f; }

// MLP1: feat[9] -> relu(9x32) -> relu(32x32) -> sigmoid(32x1)
// Weights via compile-time-indexed const __restrict__ -> scalarized s_load.
__device__ __forceinline__ float mlp1_eval_g(const float* feat,
                                             const float* __restrict__ w1,
                                             const float* __restrict__ b1,
                                             const float* __restrict__ w2,
                                             const float* __restrict__ b2,
                                             const float* __restrict__ w3,
                                             const float* __restrict__ b3) {
    float h1[32];
#pragma unroll
    for (int j = 0; j < 32; ++j) h1[j] = b1[j];
#pragma unroll
    for (int i = 0; i < 9; ++i) {
        float f = feat[i];
#pragma unroll
        for (int j = 0; j < 32; ++j) h1[j] += f * w1[i * 32 + j];
    }
#pragma unroll
    for (int j = 0; j < 32; ++j) h1[j] = reluf_(h1[j]);

    float h2[32];
#pragma unroll
    for (int j = 0; j < 32; ++j) h2[j] = b2[j];
#pragma unroll
    for (int i = 0; i < 32; ++i) {
        float f = h1[i];
#pragma unroll
        for (int j = 0; j < 32; ++j) h2[j] += f * w2[i * 32 + j];
    }
    float acc = b3[0];
#pragma unroll
    for (int j = 0; j < 32; ++j) acc += reluf_(h2[j]) * w3[j];
    return sigmoidf_(acc);
}

// Pre-pass. Grid covers EE threads when use_eaT (edge-attr transpose), else NN.
__global__ void pre_kernel(const float* __restrict__ x,
                           const float* __restrict__ ea,
                           const float* __restrict__ w1, const float* __restrict__ b1,
                           const float* __restrict__ w2, const float* __restrict__ b2,
                           const float* __restrict__ w3, const float* __restrict__ b3,
                           float* __restrict__ hidden, float* __restrict__ msg_base,
                           float* __restrict__ agg,
                           float* __restrict__ x0T, float* __restrict__ x1T,
                           float* __restrict__ eaT, int binned, int use_eaT) {
    int g = blockIdx.x * blockDim.x + threadIdx.x;
    if (use_eaT && g < EE) {
        const float2* row = reinterpret_cast<const float2*>(ea + (size_t)g * TT);
        float v[TT];
#pragma unroll
        for (int c = 0; c < 5; ++c) { float2 p = row[c]; v[2 * c] = p.x; v[2 * c + 1] = p.y; }
#pragma unroll
        for (int tt = 0; tt < TT; ++tt) eaT[(size_t)tt * EE + g] = v[tt];
    }
    if (g >= NN) return;
    float x00;
    if (binned) {
        const float2* xr = reinterpret_cast<const float2*>(x + (size_t)g * TT * 2);
        float x0v[TT], x1v[TT];
#pragma unroll
        for (int tt = 0; tt < TT; ++tt) { float2 p = xr[tt]; x0v[tt] = p.x; x1v[tt] = p.y; }
#pragma unroll
        for (int tt = 0; tt < TT; ++tt) { x0T[tt * NN + g] = x0v[tt]; x1T[tt * NN + g] = x1v[tt]; }
        x00 = x0v[0];
    } else {
        x00 = x[(size_t)g * TT * 2];
        agg[g] = 0.0f;
    }
    float feat[9];
    feat[0] = x00;
#pragma unroll
    for (int k = 0; k < 8; ++k) feat[1 + k] = 0.0f;
    msg_base[g] = mlp1_eval_g(feat, w1, b1, w2, b2, w3, b3);
#pragma unroll
    for (int k = 0; k < 8; ++k) hidden[g * 8 + k] = 0.0f;
}

// Binned edge aggregation, no device atomics. EB_ blocks (EB_*EBT*KPT_ >= EE),
// each block LDS-bins its edges over 4 node partitions and flushes a private
// copy aggB[b][n] with float4 stores.
template <int KPT_>
__global__ __launch_bounds__(EBT) void edge_bin_kernel(const int* __restrict__ ei,
                                                       const float* __restrict__ ea,
                                                       const float* __restrict__ eaT,
                                                       const float* __restrict__ msg_base,
                                                       float* __restrict__ aggB,
                                                       int t, int use_eaT) {
    __shared__ float lacc[PART];
    const int tid = threadIdx.x;
    const int b = blockIdx.x;

    int d[KPT_];
    float m[KPT_];
#pragma unroll
    for (int k = 0; k < KPT_; ++k) {
        int e = b * (EBT * KPT_) + k * EBT + tid;
        if (e < EE) {
            d[k] = ei[(size_t)(TT + t) * EE + e];
            int s = ei[(size_t)t * EE + e];
            float w = use_eaT ? eaT[(size_t)t * EE + e] : ea[(size_t)e * TT + t];
            m[k] = msg_base[s] * w;
        } else {
            d[k] = -1;
            m[k] = 0.0f;
        }
    }

#pragma unroll
    for (int p = 0; p < NPASS; ++p) {
        const int lo = p * PART;
        float4* l4 = reinterpret_cast<float4*>(lacc);
        for (int i = tid; i < PART / 4; i += EBT) l4[i] = make_float4(0.f, 0.f, 0.f, 0.f);
        __syncthreads();
#pragma unroll
        for (int k = 0; k < KPT_; ++k) {
            int r = d[k] - lo;
            if ((unsigned)r < (unsigned)PART) atomicAdd(&lacc[r], m[k]);
        }
        __syncthreads();
        const float4* s4 = reinterpret_cast<const float4*>(lacc);
        float4* o4 = reinterpret_cast<float4*>(aggB + (size_t)b * NN + lo);
        for (int i = tid; i < PART / 4; i += EBT) o4[i] = s4[i];
        __syncthreads();
    }
}

// High-TLP reduction: agg[n] = sum_b aggB[b][n]. 8 threads per node, each
// sums EB_/8 slices with coalesced loads; LDS combine.
template <int EB_>
__global__ __launch_bounds__(256) void reduce_kernel(const float* __restrict__ aggB,
                                                     float* __restrict__ agg) {
    __shared__ float part[32 * 8];
    const int l = threadIdx.x & 31;
    const int g = threadIdx.x >> 5;
    const int n = blockIdx.x * 32 + l;
    constexpr int S = EB_ / 8;
    float acc = 0.0f;
    if (n < NN) {
#pragma unroll
        for (int j = 0; j < S; ++j) acc += aggB[(size_t)(g * S + j) * NN + n];
    }
    part[l * 8 + g] = acc;
    __syncthreads();
    if (threadIdx.x < 32) {
        int nn = blockIdx.x * 32 + threadIdx.x;
        if (nn < NN) {
            float s = 0.0f;
#pragma unroll
            for (int g2 = 0; g2 < 8; ++g2) s += part[threadIdx.x * 8 + g2];
            agg[nn] = s;
        }
    }
}

// Legacy fallback: device-atomic scatter (tiny workspace only).
__global__ void edge_kernel(const int* __restrict__ ei, const float* __restrict__ ea,
                            const float* __restrict__ msg_base, float* __restrict__ agg,
                            int t) {
    int g = blockIdx.x * blockDim.x + threadIdx.x;
    int e0 = g * 2;
    if (e0 >= EE) return;
    const int2 s = *reinterpret_cast<const int2*>(ei + (size_t)t * EE + e0);
    const int2 d = *reinterpret_cast<const int2*>(ei + (size_t)(TT + t) * EE + e0);
    atomicAdd(&agg[d.x], msg_base[s.x] * ea[(size_t)e0 * TT + t]);
    atomicAdd(&agg[d.y], msg_base[s.y] * ea[(size_t)(e0 + 1) * TT + t]);
}

// Node update for frame t: reads agg[n] (pre-reduced), MLP2 -> tanh -> hidden,
// h2o -> out, MLP1 for next frame's msg_base. Weights via scalar loads.
__global__ void node_kernel(const float* __restrict__ x,
                            const float* __restrict__ x0T, const float* __restrict__ x1T,
                            const float* __restrict__ m1w1, const float* __restrict__ m1b1,
                            const float* __restrict__ m1w2, const float* __restrict__ m1b2,
                            const float* __restrict__ m1w3, const float* __restrict__ m1b3,
                            const float* __restrict__ m2w1, const float* __restrict__ m2b1,
                            const float* __restrict__ m2w2, const float* __restrict__ m2b2,
                            const float* __restrict__ ow1, const float* __restrict__ ob1,
                            const float* __restrict__ ow2, const float* __restrict__ ob2,
                            float* __restrict__ hidden, float* __restrict__ msg_base,
                            float* __restrict__ agg, float* __restrict__ out,
                            int t, int binned) {
    int n = blockIdx.x * blockDim.x + threadIdx.x;
    if (n >= NN) return;

    float hid[8];
#pragma unroll
    for (int k = 0; k < 8; ++k) hid[k] = hidden[n * 8 + k];

    float a = agg[n];
    float x1 = binned ? x1T[t * NN + n] : x[(size_t)n * TT * 2 + t * 2 + 1];

    float uin[10];
    uin[0] = x1;
#pragma unroll
    for (int k = 0; k < 8; ++k) uin[1 + k] = hid[k];
    uin[9] = a;

    float u1[32];
#pragma unroll
    for (int j = 0; j < 32; ++j) u1[j] = m2b1[j];
#pragma unroll
    for (int i = 0; i < 10; ++i) {
        float f = uin[i];
#pragma unroll
        for (int j = 0; j < 32; ++j) u1[j] += f * m2w1[i * 32 + j];
    }
#pragma unroll
    for (int j = 0; j < 32; ++j) u1[j] = reluf_(u1[j]);

    float hn[8];
#pragma unroll
    for (int k = 0; k < 8; ++k) hn[k] = m2b2[k];
#pragma unroll
    for (int j = 0; j < 32; ++j) {
        float f = u1[j];
#pragma unroll
        for (int k = 0; k < 8; ++k) hn[k] += f * m2w2[j * 8 + k];
    }
#pragma unroll
    for (int k = 0; k < 8; ++k) hn[k] = tanhf(reluf_(hn[k]));
#pragma unroll
    for (int k = 0; k < 8; ++k) hidden[n * 8 + k] = hn[k];

    float o1[16];
#pragma unroll
    for (int l = 0; l < 16; ++l) o1[l] = ob1[l];
#pragma unroll
    for (int k = 0; k < 8; ++k) {
        float f = hn[k];
#pragma unroll
        for (int l = 0; l < 16; ++l) o1[l] += f * ow1[k * 16 + l];
    }
    float oo = ob2[0];
#pragma unroll
    for (int l = 0; l < 16; ++l) oo += reluf_(o1[l]) * ow2[l];
    out[t * NN + n] = sigmoidf_(oo);

    if (t < TT - 1) {
        float feat[9];
        feat[0] = binned ? x0T[(t + 1) * NN + n] : x[(size_t)n * TT * 2 + (t + 1) * 2];
#pragma unroll
        for (int k = 0; k < 8; ++k) feat[1 + k] = hn[k];
        msg_base[n] = mlp1_eval_g(feat, m1w1, m1b1, m1w2, m1b2, m1w3, m1b3);
        if (!binned) agg[n] = 0.0f;
    }
}

extern "C" void kernel_launch(void* const* d_in, const int* in_sizes, int n_in,
                              void* d_out, int out_size, void* d_ws, size_t ws_size,
                              hipStream_t stream) {
    (void)in_sizes; (void)n_in; (void)out_size;
    const float* x    = (const float*)d_in[0];
    const int*   ei   = (const int*)d_in[1];
    const float* ea   = (const float*)d_in[2];
    const float* m1w1 = (const float*)d_in[3];
    const float* m1b1 = (const float*)d_in[4];
    const float* m1w2 = (const float*)d_in[5];
    const float* m1b2 = (const float*)d_in[6];
    const float* m1w3 = (const float*)d_in[7];
    const float* m1b3 = (const float*)d_in[8];
    const float* m2w1 = (const float*)d_in[9];
    const float* m2b1 = (const float*)d_in[10];
    const float* m2w2 = (const float*)d_in[11];
    const float* m2b2 = (const float*)d_in[12];
    const float* ow1  = (const float*)d_in[13];
    const float* ob1  = (const float*)d_in[14];
    const float* ow2  = (const float*)d_in[15];
    const float* ob2  = (const float*)d_in[16];
    float* out = (float*)d_out;

    float* hidden   = (float*)d_ws;             // NN*8
    float* msg_base = hidden + (size_t)NN * 8;  // NN
    float* agg      = msg_base + NN;            // NN
    float* x0T      = agg + NN;                 // NN*TT
    float* x1T      = x0T + (size_t)NN * TT;    // NN*TT
    float* aggB     = x1T + (size_t)NN * TT;    // EB*NN
    // eaT sits after aggB (size depends on EB tier)

    const size_t base_f = (size_t)NN * 8 + NN + NN + (size_t)NN * TT * 2;
    const size_t need256 = (base_f + (size_t)256 * NN) * sizeof(float);
    const size_t need128 = (base_f + (size_t)128 * NN) * sizeof(float);
    const size_t eaT_f   = (size_t)EE * TT;

    int EB = 0, use_eaT = 0, binned = 1;
    if (ws_size >= need256 + eaT_f * sizeof(float)) { EB = 256; use_eaT = 1; }
    else if (ws_size >= need256) { EB = 256; }
    else if (ws_size >= need128) { EB = 128; }
    else { binned = 0; }

    float* eaT = aggB + (size_t)EB * NN;

    dim3 blk(256);
    int nodeBlocks = (NN + 255) / 256;
    int preBlocks = use_eaT ? (EE + 255) / 256 : nodeBlocks;
    int reduceBlocks = (NN + 31) / 32;
    int edgeBlocksLegacy = (EE / 2 + 255) / 256;

    pre_kernel<<<preBlocks, blk, 0, stream>>>(x, ea, m1w1, m1b1, m1w2, m1b2, m1w3, m1b3,
                                              hidden, msg_base, agg, x0T, x1T, eaT,
                                              binned, use_eaT);
    for (int t = 0; t < TT; ++t) {
        if (binned) {
            if (EB == 256) {
                edge_bin_kernel<4><<<256, dim3(EBT), 0, stream>>>(ei, ea, eaT, msg_base,
                                                                  aggB, t, use_eaT);
                reduce_kernel<256><<<reduceBlocks, blk, 0, stream>>>(aggB, agg);
            } else {
                edge_bin_kernel<8><<<128, dim3(EBT), 0, stream>>>(ei, ea, eaT, msg_base,
                                                                  aggB, t, use_eaT);
                reduce_kernel<128><<<reduceBlocks, blk, 0, stream>>>(aggB, agg);
            }
        } else {
            edge_kernel<<<edgeBlocksLegacy, blk, 0, stream>>>(ei, ea, msg_base, agg, t);
        }
        node_kernel<<<nodeBlocks, blk, 0, stream>>>(x, x0T, x1T,
                                                    m1w1, m1b1, m1w2, m1b2, m1w3, m1b3,
                                                    m2w1, m2b1, m2w2, m2b2,
                                                    ow1, ob1, ow2, ob2,
                                                    hidden, msg_base, agg, out, t, binned);
    }
}

// Round 4
// 759.535 us; speedup vs baseline: 1.8172x; 1.0834x over previous
//
#include <hip/hip_runtime.h>

#define NN 50000
#define TT 10
#define EE 1000000

#define EBT 1024     // threads per edge block
#define EB 128       // edge blocks == aggB copies
#define KPT 8        // edges per thread in edge kernel
#define PART 12500   // nodes per LDS partition (48.8 KB)
#define NPASS 4      // PART * NPASS == NN

__device__ __forceinline__ float sigmoidf_(float v) { return 1.0f / (1.0f + __expf(-v)); }
__device__ __forceinline__ float reluf_(float v) { return v > 0.0f ? v : 0.0f; }

__device__ __forceinline__ float4 ld4_(const float* __restrict__ p) {
    return *reinterpret_cast<const float4*>(p);
}
// acc[0..7] += f * w[0..7]
__device__ __forceinline__ void fma_row8(float* acc, const float* __restrict__ w, float f) {
    float4 a = ld4_(w), b = ld4_(w + 4);
    acc[0] += f * a.x; acc[1] += f * a.y; acc[2] += f * a.z; acc[3] += f * a.w;
    acc[4] += f * b.x; acc[5] += f * b.y; acc[6] += f * b.z; acc[7] += f * b.w;
}

// Serial MLP1 (used only in pre_kernel, hidden under the transpose work).
__device__ __forceinline__ float mlp1_eval_g(const float* feat,
                                             const float* __restrict__ w1,
                                             const float* __restrict__ b1,
                                             const float* __restrict__ w2,
                                             const float* __restrict__ b2,
                                             const float* __restrict__ w3,
                                             const float* __restrict__ b3) {
    float h1[32];
#pragma unroll
    for (int j = 0; j < 32; ++j) h1[j] = b1[j];
#pragma unroll
    for (int i = 0; i < 9; ++i) {
        float f = feat[i];
#pragma unroll
        for (int j = 0; j < 32; ++j) h1[j] += f * w1[i * 32 + j];
    }
#pragma unroll
    for (int j = 0; j < 32; ++j) h1[j] = reluf_(h1[j]);
    float h2[32];
#pragma unroll
    for (int j = 0; j < 32; ++j) h2[j] = b2[j];
#pragma unroll
    for (int i = 0; i < 32; ++i) {
        float f = h1[i];
#pragma unroll
        for (int j = 0; j < 32; ++j) h2[j] += f * w2[i * 32 + j];
    }
    float acc = b3[0];
#pragma unroll
    for (int j = 0; j < 32; ++j) acc += reluf_(h2[j]) * w3[j];
    return sigmoidf_(acc);
}

// Pre-pass: eaT/x transposes (binned) + init (hidden=0, msg_base frame 0, agg=0 legacy).
__global__ void pre_kernel(const float* __restrict__ x,
                           const float* __restrict__ ea,
                           const float* __restrict__ w1, const float* __restrict__ b1,
                           const float* __restrict__ w2, const float* __restrict__ b2,
                           const float* __restrict__ w3, const float* __restrict__ b3,
                           float* __restrict__ hidden, float* __restrict__ msg_base,
                           float* __restrict__ agg,
                           float* __restrict__ x0T, float* __restrict__ x1T,
                           float* __restrict__ eaT, int binned, int use_eaT) {
    int g = blockIdx.x * blockDim.x + threadIdx.x;
    if (use_eaT && g < EE) {
        const float2* row = reinterpret_cast<const float2*>(ea + (size_t)g * TT);
        float v[TT];
#pragma unroll
        for (int c = 0; c < 5; ++c) { float2 p = row[c]; v[2 * c] = p.x; v[2 * c + 1] = p.y; }
#pragma unroll
        for (int tt = 0; tt < TT; ++tt) eaT[(size_t)tt * EE + g] = v[tt];
    }
    if (g >= NN) return;
    float x00;
    if (binned) {
        const float2* xr = reinterpret_cast<const float2*>(x + (size_t)g * TT * 2);
        float x0v[TT], x1v[TT];
#pragma unroll
        for (int tt = 0; tt < TT; ++tt) { float2 p = xr[tt]; x0v[tt] = p.x; x1v[tt] = p.y; }
#pragma unroll
        for (int tt = 0; tt < TT; ++tt) { x0T[tt * NN + g] = x0v[tt]; x1T[tt * NN + g] = x1v[tt]; }
        x00 = x0v[0];
    } else {
        x00 = x[(size_t)g * TT * 2];
    }
    agg[g] = 0.0f;
    float feat[9];
    feat[0] = x00;
#pragma unroll
    for (int k = 0; k < 8; ++k) feat[1 + k] = 0.0f;
    msg_base[g] = mlp1_eval_g(feat, w1, b1, w2, b2, w3, b3);
#pragma unroll
    for (int k = 0; k < 8; ++k) hidden[g * 8 + k] = 0.0f;
}

// Binned edge aggregation, no device atomics. EB blocks, each LDS-bins its
// 7813 edges over 4 node partitions and flushes a private copy aggB[b][n].
__global__ __launch_bounds__(EBT) void edge_bin_kernel(const int* __restrict__ ei,
                                                       const float* __restrict__ ea,
                                                       const float* __restrict__ eaT,
                                                       const float* __restrict__ msg_base,
                                                       float* __restrict__ aggB,
                                                       int t, int use_eaT) {
    __shared__ float lacc[PART];
    const int tid = threadIdx.x;
    const int b = blockIdx.x;

    int d[KPT];
    float m[KPT];
#pragma unroll
    for (int k = 0; k < KPT; ++k) {
        int e = b * (EBT * KPT) + k * EBT + tid;
        if (e < EE) {
            d[k] = ei[(size_t)(TT + t) * EE + e];
            int s = ei[(size_t)t * EE + e];
            float w = use_eaT ? eaT[(size_t)t * EE + e] : ea[(size_t)e * TT + t];
            m[k] = msg_base[s] * w;
        } else {
            d[k] = -1;
            m[k] = 0.0f;
        }
    }

#pragma unroll
    for (int p = 0; p < NPASS; ++p) {
        const int lo = p * PART;
        float4* l4 = reinterpret_cast<float4*>(lacc);
        for (int i = tid; i < PART / 4; i += EBT) l4[i] = make_float4(0.f, 0.f, 0.f, 0.f);
        __syncthreads();
#pragma unroll
        for (int k = 0; k < KPT; ++k) {
            int r = d[k] - lo;
            if ((unsigned)r < (unsigned)PART) atomicAdd(&lacc[r], m[k]);
        }
        __syncthreads();
        const float4* s4 = reinterpret_cast<const float4*>(lacc);
        float4* o4 = reinterpret_cast<float4*>(aggB + (size_t)b * NN + lo);
        for (int i = tid; i < PART / 4; i += EBT) o4[i] = s4[i];
        __syncthreads();
    }
}

// Legacy fallback: device-atomic scatter.
__global__ void edge_kernel(const int* __restrict__ ei, const float* __restrict__ ea,
                            const float* __restrict__ msg_base, float* __restrict__ agg,
                            int t) {
    int g = blockIdx.x * blockDim.x + threadIdx.x;
    int e0 = g * 2;
    if (e0 >= EE) return;
    const int2 s = *reinterpret_cast<const int2*>(ei + (size_t)t * EE + e0);
    const int2 d = *reinterpret_cast<const int2*>(ei + (size_t)(TT + t) * EE + e0);
    atomicAdd(&agg[d.x], msg_base[s.x] * ea[(size_t)e0 * TT + t]);
    atomicAdd(&agg[d.y], msg_base[s.y] * ea[(size_t)(e0 + 1) * TT + t]);
}

// 4-lane-per-node node update. Lane q of node n computes MLP columns
// [q*8, q*8+8); activations recovered via quad __shfl_xor. Register arrays
// are only ever statically indexed; the quad permutation (slot g -> column
// block q^g) is folded into runtime weight-load ADDRESSES.
// Also fuses the aggB reduction (lane q sums EB/4 copies).
template <int EB_, int BINNED>
__global__ __launch_bounds__(256) void node4_kernel(
        const float* __restrict__ x,
        const float* __restrict__ x0T, const float* __restrict__ x1T,
        const float* __restrict__ m1w1, const float* __restrict__ m1b1,
        const float* __restrict__ m1w2, const float* __restrict__ m1b2,
        const float* __restrict__ m1w3, const float* __restrict__ m1b3,
        const float* __restrict__ m2w1, const float* __restrict__ m2b1,
        const float* __restrict__ m2w2, const float* __restrict__ m2b2,
        const float* __restrict__ ow1, const float* __restrict__ ob1,
        const float* __restrict__ ow2, const float* __restrict__ ob2,
        float* __restrict__ hidden, float* __restrict__ msg_base,
        float* __restrict__ agg, const float* __restrict__ aggB,
        float* __restrict__ out, int t) {
    const int gid = blockIdx.x * 256 + threadIdx.x;
    const int n = gid >> 2;
    const int q = gid & 3;
    if (n >= NN) return;

    // ---- aggregate input a ----
    float a;
    if (BINNED) {
        constexpr int S = EB_ / 4;
        const float* p = aggB + (size_t)(q * S) * NN + n;
        float s = 0.0f;
#pragma unroll
        for (int j = 0; j < S; ++j) s += p[(size_t)j * NN];
        s += __shfl_xor(s, 1);
        s += __shfl_xor(s, 2);
        a = s;
    } else {
        a = agg[n];
    }

    const float x1 = BINNED ? x1T[t * NN + n] : x[(size_t)n * TT * 2 + t * 2 + 1];

    // ---- hidden: own float2, exchange for permuted full set ----
    // hid[g*2+jj] holds hidden[n*8 + (q^g)*2 + jj]
    float2 hme = *reinterpret_cast<const float2*>(hidden + (size_t)n * 8 + q * 2);
    float hid[8];
    hid[0] = hme.x; hid[1] = hme.y;
    hid[2] = __shfl_xor(hid[0], 1); hid[3] = __shfl_xor(hid[1], 1);
    hid[4] = __shfl_xor(hid[0], 2); hid[5] = __shfl_xor(hid[1], 2);
    hid[6] = __shfl_xor(hid[2], 2); hid[7] = __shfl_xor(hid[3], 2);

    // ---- MLP2 layer1: u1 columns [q*8, q*8+8) ----
    float acc[8];
    {
        float4 bA = ld4_(m2b1 + q * 8), bB = ld4_(m2b1 + q * 8 + 4);
        acc[0] = bA.x; acc[1] = bA.y; acc[2] = bA.z; acc[3] = bA.w;
        acc[4] = bB.x; acc[5] = bB.y; acc[6] = bB.z; acc[7] = bB.w;
    }
    fma_row8(acc, m2w1 + q * 8, x1);  // row 0 = x1
#pragma unroll
    for (int g = 0; g < 4; ++g) {
        int rq = (q ^ g) * 2;
        fma_row8(acc, m2w1 + (size_t)(1 + rq) * 32 + q * 8, hid[g * 2 + 0]);
        fma_row8(acc, m2w1 + (size_t)(2 + rq) * 32 + q * 8, hid[g * 2 + 1]);
    }
    fma_row8(acc, m2w1 + (size_t)9 * 32 + q * 8, a);  // row 9 = agg
    float u1[8];
#pragma unroll
    for (int jj = 0; jj < 8; ++jj) u1[jj] = reluf_(acc[jj]);

    // ---- MLP2 layer2: quad-partial over own 8 rows, reduce -> all lanes hold hn[0..7]
    float pk[8];
#pragma unroll
    for (int k = 0; k < 8; ++k) pk[k] = 0.0f;
#pragma unroll
    for (int jj = 0; jj < 8; ++jj)
        fma_row8(pk, m2w2 + (size_t)(q * 8 + jj) * 8, u1[jj]);
#pragma unroll
    for (int k = 0; k < 8; ++k) {
        pk[k] += __shfl_xor(pk[k], 1);
        pk[k] += __shfl_xor(pk[k], 2);
    }
    float hn[8];
    {
        float4 b2A = ld4_(m2b2), b2B = ld4_(m2b2 + 4);
        hn[0] = tanhf(reluf_(pk[0] + b2A.x));
        hn[1] = tanhf(reluf_(pk[1] + b2A.y));
        hn[2] = tanhf(reluf_(pk[2] + b2A.z));
        hn[3] = tanhf(reluf_(pk[3] + b2A.w));
        hn[4] = tanhf(reluf_(pk[4] + b2B.x));
        hn[5] = tanhf(reluf_(pk[5] + b2B.y));
        hn[6] = tanhf(reluf_(pk[6] + b2B.z));
        hn[7] = tanhf(reluf_(pk[7] + b2B.w));
    }
    if (q == 0) {
        *reinterpret_cast<float4*>(hidden + (size_t)n * 8)     = make_float4(hn[0], hn[1], hn[2], hn[3]);
        *reinterpret_cast<float4*>(hidden + (size_t)n * 8 + 4) = make_float4(hn[4], hn[5], hn[6], hn[7]);
    }

    // ---- h2o: o1 columns [q*4, q*4+4) ----
    float o1v[4];
    {
        float4 ob = ld4_(ob1 + q * 4);
        o1v[0] = ob.x; o1v[1] = ob.y; o1v[2] = ob.z; o1v[3] = ob.w;
    }
#pragma unroll
    for (int k = 0; k < 8; ++k) {
        float4 w = ld4_(ow1 + k * 16 + q * 4);
        o1v[0] += hn[k] * w.x; o1v[1] += hn[k] * w.y;
        o1v[2] += hn[k] * w.z; o1v[3] += hn[k] * w.w;
    }
    {
        float4 w2v = ld4_(ow2 + q * 4);
        float oop = reluf_(o1v[0]) * w2v.x + reluf_(o1v[1]) * w2v.y +
                    reluf_(o1v[2]) * w2v.z + reluf_(o1v[3]) * w2v.w;
        oop += __shfl_xor(oop, 1);
        oop += __shfl_xor(oop, 2);
        if (q == 0) out[t * NN + n] = sigmoidf_(oop + ob2[0]);
    }

    // ---- MLP1 for next frame's msg_base ----
    if (t < TT - 1) {
        float feat0 = BINNED ? x0T[(t + 1) * NN + n] : x[(size_t)n * TT * 2 + (t + 1) * 2];
        float h1[8];
        {
            float4 bA = ld4_(m1b1 + q * 8), bB = ld4_(m1b1 + q * 8 + 4);
            h1[0] = bA.x; h1[1] = bA.y; h1[2] = bA.z; h1[3] = bA.w;
            h1[4] = bB.x; h1[5] = bB.y; h1[6] = bB.z; h1[7] = bB.w;
        }
        fma_row8(h1, m1w1 + q * 8, feat0);  // row 0
#pragma unroll
        for (int k = 0; k < 8; ++k)
            fma_row8(h1, m1w1 + (size_t)(1 + k) * 32 + q * 8, hn[k]);
#pragma unroll
        for (int jj = 0; jj < 8; ++jj) h1[jj] = reluf_(h1[jj]);

        // exchange: h1x[g*8+jj] = h1 of lane q^g = column (q^g)*8+jj
        float h1x[32];
#pragma unroll
        for (int jj = 0; jj < 8; ++jj) h1x[jj] = h1[jj];
#pragma unroll
        for (int jj = 0; jj < 8; ++jj) h1x[8 + jj]  = __shfl_xor(h1x[jj], 1);
#pragma unroll
        for (int jj = 0; jj < 8; ++jj) h1x[16 + jj] = __shfl_xor(h1x[jj], 2);
#pragma unroll
        for (int jj = 0; jj < 8; ++jj) h1x[24 + jj] = __shfl_xor(h1x[8 + jj], 2);

        float acc8[8];
        {
            float4 bA = ld4_(m1b2 + q * 8), bB = ld4_(m1b2 + q * 8 + 4);
            acc8[0] = bA.x; acc8[1] = bA.y; acc8[2] = bA.z; acc8[3] = bA.w;
            acc8[4] = bB.x; acc8[5] = bB.y; acc8[6] = bB.z; acc8[7] = bB.w;
        }
#pragma unroll
        for (int g = 0; g < 4; ++g) {
            int rb = (q ^ g) * 8;
#pragma unroll
            for (int jj = 0; jj < 8; ++jj)
                fma_row8(acc8, m1w2 + (size_t)(rb + jj) * 32 + q * 8, h1x[g * 8 + jj]);
        }
        float s3;
        {
            float4 w3a = ld4_(m1w3 + q * 8), w3b = ld4_(m1w3 + q * 8 + 4);
            s3 = reluf_(acc8[0]) * w3a.x + reluf_(acc8[1]) * w3a.y +
                 reluf_(acc8[2]) * w3a.z + reluf_(acc8[3]) * w3a.w +
                 reluf_(acc8[4]) * w3b.x + reluf_(acc8[5]) * w3b.y +
                 reluf_(acc8[6]) * w3b.z + reluf_(acc8[7]) * w3b.w;
        }
        s3 += __shfl_xor(s3, 1);
        s3 += __shfl_xor(s3, 2);
        if (q == 0) {
            msg_base[n] = sigmoidf_(s3 + m1b3[0]);
            if (!BINNED) agg[n] = 0.0f;
        }
    }
}

extern "C" void kernel_launch(void* const* d_in, const int* in_sizes, int n_in,
                              void* d_out, int out_size, void* d_ws, size_t ws_size,
                              hipStream_t stream) {
    (void)in_sizes; (void)n_in; (void)out_size;
    const float* x    = (const float*)d_in[0];
    const int*   ei   = (const int*)d_in[1];
    const float* ea   = (const float*)d_in[2];
    const float* m1w1 = (const float*)d_in[3];
    const float* m1b1 = (const float*)d_in[4];
    const float* m1w2 = (const float*)d_in[5];
    const float* m1b2 = (const float*)d_in[6];
    const float* m1w3 = (const float*)d_in[7];
    const float* m1b3 = (const float*)d_in[8];
    const float* m2w1 = (const float*)d_in[9];
    const float* m2b1 = (const float*)d_in[10];
    const float* m2w2 = (const float*)d_in[11];
    const float* m2b2 = (const float*)d_in[12];
    const float* ow1  = (const float*)d_in[13];
    const float* ob1  = (const float*)d_in[14];
    const float* ow2  = (const float*)d_in[15];
    const float* ob2  = (const float*)d_in[16];
    float* out = (float*)d_out;

    float* hidden   = (float*)d_ws;             // NN*8
    float* msg_base = hidden + (size_t)NN * 8;  // NN
    float* agg      = msg_base + NN;            // NN (legacy)
    float* x0T      = agg + NN;                 // NN*TT
    float* x1T      = x0T + (size_t)NN * TT;    // NN*TT
    float* aggB     = x1T + (size_t)NN * TT;    // EB*NN
    float* eaT      = aggB + (size_t)EB * NN;   // EE*TT

    const size_t base_f = (size_t)NN * 8 + NN + NN + (size_t)NN * TT * 2;
    const size_t needB   = (base_f + (size_t)EB * NN) * sizeof(float);
    const size_t needBT  = needB + (size_t)EE * TT * sizeof(float);

    int binned = 0, use_eaT = 0;
    if (ws_size >= needBT) { binned = 1; use_eaT = 1; }
    else if (ws_size >= needB) { binned = 1; }

    dim3 blk(256);
    int nodeBlocks  = (NN + 255) / 256;           // pre (node part)
    int node4Blocks = (NN * 4 + 255) / 256;       // 4-lane node kernel
    int preBlocks   = use_eaT ? (EE + 255) / 256 : nodeBlocks;
    int edgeBlocksLegacy = (EE / 2 + 255) / 256;

    pre_kernel<<<preBlocks, blk, 0, stream>>>(x, ea, m1w1, m1b1, m1w2, m1b2, m1w3, m1b3,
                                              hidden, msg_base, agg, x0T, x1T, eaT,
                                              binned, use_eaT);
    for (int t = 0; t < TT; ++t) {
        if (binned) {
            edge_bin_kernel<<<EB, dim3(EBT), 0, stream>>>(ei, ea, eaT, msg_base, aggB,
                                                          t, use_eaT);
            node4_kernel<EB, 1><<<node4Blocks, blk, 0, stream>>>(
                x, x0T, x1T,
                m1w1, m1b1, m1w2, m1b2, m1w3, m1b3,
                m2w1, m2b1, m2w2, m2b2,
                ow1, ob1, ow2, ob2,
                hidden, msg_base, agg, aggB, out, t);
        } else {
            edge_kernel<<<edgeBlocksLegacy, blk, 0, stream>>>(ei, ea, msg_base, agg, t);
            node4_kernel<EB, 0><<<node4Blocks, blk, 0, stream>>>(
                x, x0T, x1T,
                m1w1, m1b1, m1w2, m1b2, m1w3, m1b3,
                m2w1, m2b1, m2w2, m2b2,
                ow1, ob1, ow2, ob2,
                hidden, msg_base, agg, aggB, out, t);
        }
    }
}